// Round 1
// baseline (4305.639 us; speedup 1.0000x reference)
//
#include <hip/hip_runtime.h>
#include <hip/hip_bf16.h>

// ---------------------------------------------------------------------------
// Trojan_GCN: 2x GraphConv (norm='both') + ReLU, then two 2-layer MLPs on
// gathered trigger nodes. All f32 compute.
//
// inputs (in_sizes order):
//  0 features [N,128] f32      1 src [E] i32        2 dst [E] i32
//  3 trigger_nodes [T] i32     4 W1 [128,256]       5 b1 [256]
//  6 W2 [256,128]              7 b2 [128]           8 Wf [128,128]
//  9 bf [128]                 10 Wf1 [128,128]     11 bf1 [128]
// 12 We [128,64]              13 be [64]           14 We1 [64,64]
// 15 be1 [64]
// output: concat(feat [T,128], edge_weight [T,64]) f32
// ---------------------------------------------------------------------------

__global__ __launch_bounds__(256) void deg_kernel(
    const int* __restrict__ src, const int* __restrict__ dst,
    float* __restrict__ deg_out, float* __restrict__ deg_in, int E)
{
    int i = blockIdx.x * blockDim.x + threadIdx.x;
    if (i < E) {
        atomicAdd(&deg_out[src[i]], 1.0f);
        atomicAdd(&deg_in[dst[i]], 1.0f);
    }
}

__global__ __launch_bounds__(256) void norm_kernel(
    float* __restrict__ deg_out, float* __restrict__ deg_in, int N)
{
    int i = blockIdx.x * blockDim.x + threadIdx.x;
    if (i < N) {
        deg_out[i] = rsqrtf(fmaxf(deg_out[i], 1.0f));
        deg_in[i]  = rsqrtf(fmaxf(deg_in[i], 1.0f));
    }
}

// agg[dst[e], :] += x[src[e], :] * norm_out[src[e]]   (one float4 per thread)
template<int D>
__global__ __launch_bounds__(256) void scatter_kernel(
    const float* __restrict__ x, const float* __restrict__ norm_out,
    const int* __restrict__ src, const int* __restrict__ dst,
    float* __restrict__ agg, long E)
{
    const int VPE = D / 4;                 // float4 slots per edge
    long total = E * (long)VPE;
    long stride = (long)gridDim.x * blockDim.x;
    for (long idx = (long)blockIdx.x * blockDim.x + threadIdx.x;
         idx < total; idx += stride) {
        long e = idx / VPE;
        int  q = (int)(idx - e * VPE);
        int  s = src[e];
        int  t = dst[e];
        float ns = norm_out[s];
        const float4 v = *reinterpret_cast<const float4*>(&x[(long)s * D + q * 4]);
        float* o = &agg[(long)t * D + q * 4];
        atomicAdd(o + 0, v.x * ns);
        atomicAdd(o + 1, v.y * ns);
        atomicAdd(o + 2, v.z * ns);
        atomicAdd(o + 3, v.w * ns);
    }
}

// C[r, c] = act( sum_k rowscale[r'] * A[r', k] * B[k, c] + bias[c] )
// r' = gidx ? gidx[r] : r.  64x64 tile, 256 threads, 4x4 microtile.
// Requires: N % 64 == 0, K % 16 == 0 (M may be ragged).
template<bool RELU, bool GATHER>
__global__ __launch_bounds__(256) void gemm_kernel(
    const float* __restrict__ A, const float* __restrict__ B,
    const float* __restrict__ bias, const float* __restrict__ rowscale,
    const int* __restrict__ gidx,
    float* __restrict__ C, int M, int N, int K)
{
    constexpr int TS = 64, KT = 16;
    __shared__ float As[KT][TS + 1];
    __shared__ float Bs[KT][TS + 1];

    const int tid = threadIdx.x;
    const int tx = tid & 15, ty = tid >> 4;
    const int row0 = blockIdx.y * TS;
    const int col0 = blockIdx.x * TS;

    // A-tile load role: one float4 per thread. m = row-in-tile, q = k-quad.
    const int am = tid >> 2, aq = tid & 3;
    const int arow = row0 + am;
    const bool avalid = (arow < M);
    long asrc = arow;
    float ascale = 1.0f;
    if (avalid) {
        if (GATHER) asrc = gidx[arow];
        if (rowscale) ascale = rowscale[asrc];
    }
    // B-tile load role: one float4 per thread. bk = k-in-tile, bq = col-quad.
    const int bk = tid >> 4, bq = tid & 15;

    float acc[4][4] = {};

    for (int kb = 0; kb < K; kb += KT) {
        float4 av = make_float4(0.f, 0.f, 0.f, 0.f);
        if (avalid)
            av = *reinterpret_cast<const float4*>(&A[asrc * K + kb + aq * 4]);
        const float4 bv =
            *reinterpret_cast<const float4*>(&B[(long)(kb + bk) * N + col0 + bq * 4]);

        As[aq * 4 + 0][am] = av.x * ascale;
        As[aq * 4 + 1][am] = av.y * ascale;
        As[aq * 4 + 2][am] = av.z * ascale;
        As[aq * 4 + 3][am] = av.w * ascale;
        Bs[bk][bq * 4 + 0] = bv.x;
        Bs[bk][bq * 4 + 1] = bv.y;
        Bs[bk][bq * 4 + 2] = bv.z;
        Bs[bk][bq * 4 + 3] = bv.w;
        __syncthreads();

        #pragma unroll
        for (int kk = 0; kk < KT; ++kk) {
            float a[4], b[4];
            #pragma unroll
            for (int i = 0; i < 4; ++i) a[i] = As[kk][ty * 4 + i];
            #pragma unroll
            for (int j = 0; j < 4; ++j) b[j] = Bs[kk][tx * 4 + j];
            #pragma unroll
            for (int i = 0; i < 4; ++i)
                #pragma unroll
                for (int j = 0; j < 4; ++j)
                    acc[i][j] = fmaf(a[i], b[j], acc[i][j]);
        }
        __syncthreads();
    }

    #pragma unroll
    for (int i = 0; i < 4; ++i) {
        const int r = row0 + ty * 4 + i;
        if (r >= M) continue;
        #pragma unroll
        for (int j = 0; j < 4; ++j) {
            const int c = col0 + tx * 4 + j;
            float v = acc[i][j] + bias[c];
            if (RELU) v = fmaxf(v, 0.0f);
            C[(long)r * N + c] = v;
        }
    }
}

extern "C" void kernel_launch(void* const* d_in, const int* in_sizes, int n_in,
                              void* d_out, int out_size, void* d_ws, size_t ws_size,
                              hipStream_t stream)
{
    const float* features = (const float*)d_in[0];
    const int*   src      = (const int*)d_in[1];
    const int*   dst      = (const int*)d_in[2];
    const int*   trig     = (const int*)d_in[3];
    const float* W1  = (const float*)d_in[4];
    const float* b1  = (const float*)d_in[5];
    const float* W2  = (const float*)d_in[6];
    const float* b2  = (const float*)d_in[7];
    const float* Wf  = (const float*)d_in[8];
    const float* bf  = (const float*)d_in[9];
    const float* Wf1 = (const float*)d_in[10];
    const float* bf1 = (const float*)d_in[11];
    const float* We  = (const float*)d_in[12];
    const float* be  = (const float*)d_in[13];
    const float* We1 = (const float*)d_in[14];
    const float* be1 = (const float*)d_in[15];

    const int  d  = 128, h2d = 256, od = 64;
    const int  N  = in_sizes[0] / d;       // 50000
    const long E  = in_sizes[1];           // 800000
    const int  T  = in_sizes[3];           // 4096

    // workspace layout (floats)
    const long NP = (long)((N + 63) & ~63);
    float* ws       = (float*)d_ws;
    float* norm_out = ws;                  // N (deg_out -> norm_out in place)
    float* norm_in  = ws + NP;             // N
    float* agg1     = ws + 2 * NP;         // N*128 (later reused as h2)
    float* h1       = agg1 + (long)N * d;  // N*256
    float* agg2     = h1 + (long)N * h2d;  // N*256 (later reused as MLP temps)
    float* hh2      = agg1;                // reuse: [N,128]
    float* tmpf     = agg2;                // reuse: [T,128]
    float* tmpe     = agg2 + (long)T * d;  // reuse: [T,64]

    float* out_feat = (float*)d_out;               // [T,128]
    float* out_edge = out_feat + (long)T * d;      // [T,64]

    // zero accumulators (graph-capture-safe)
    hipMemsetAsync(norm_out, 0, (size_t)(2 * NP) * sizeof(float), stream);
    hipMemsetAsync(agg1, 0, (size_t)N * d   * sizeof(float), stream);
    hipMemsetAsync(agg2, 0, (size_t)N * h2d * sizeof(float), stream);

    // degrees -> norms
    deg_kernel<<<dim3((E + 255) / 256), dim3(256), 0, stream>>>(
        src, dst, norm_out, norm_in, (int)E);
    norm_kernel<<<dim3((N + 255) / 256), dim3(256), 0, stream>>>(
        norm_out, norm_in, N);

    // layer 1: agg1 = scatter(features * norm_out); h1 = relu(norm_in*agg1 @ W1 + b1)
    scatter_kernel<128><<<dim3(8192), dim3(256), 0, stream>>>(
        features, norm_out, src, dst, agg1, E);
    gemm_kernel<true, false><<<dim3(h2d / 64, (N + 63) / 64), dim3(256), 0, stream>>>(
        agg1, W1, b1, norm_in, nullptr, h1, N, h2d, d);

    // layer 2: agg2 = scatter(h1 * norm_out); h2 = relu(norm_in*agg2 @ W2 + b2)
    scatter_kernel<256><<<dim3(8192), dim3(256), 0, stream>>>(
        h1, norm_out, src, dst, agg2, E);
    gemm_kernel<true, false><<<dim3(d / 64, (N + 63) / 64), dim3(256), 0, stream>>>(
        agg2, W2, b2, norm_in, nullptr, hh2, N, d, h2d);

    // feat head: tmpf = relu(h2[trig] @ Wf + bf); out_feat = tmpf @ Wf1 + bf1
    gemm_kernel<true, true><<<dim3(d / 64, T / 64), dim3(256), 0, stream>>>(
        hh2, Wf, bf, nullptr, trig, tmpf, T, d, d);
    gemm_kernel<false, false><<<dim3(d / 64, T / 64), dim3(256), 0, stream>>>(
        tmpf, Wf1, bf1, nullptr, nullptr, out_feat, T, d, d);

    // edge head: tmpe = relu(h2[trig] @ We + be); out_edge = tmpe @ We1 + be1
    gemm_kernel<true, true><<<dim3(od / 64, T / 64), dim3(256), 0, stream>>>(
        hh2, We, be, nullptr, trig, tmpe, T, od, d);
    gemm_kernel<false, false><<<dim3(od / 64, T / 64), dim3(256), 0, stream>>>(
        tmpe, We1, be1, nullptr, nullptr, out_edge, T, od, od);
}

// Round 2
// 520.057 us; speedup vs baseline: 8.2792x; 8.2792x over previous
//
#include <hip/hip_runtime.h>
#include <hip/hip_bf16.h>

// ---------------------------------------------------------------------------
// Trojan_GCN round 2: CSR-gather aggregation (no float atomics).
// Pipeline per call:
//   int deg histograms -> norms; prefix-scan deg_in -> rowptr; slot-fill ecol;
//   xs = features*norm_out; agg1 = gatherSum(xs); h1s = relu(ni*agg1@W1+b1)*no;
//   agg2 = gatherSum(h1s);  h2 = relu(ni*agg2@W2+b2); two 2-layer MLP heads on
//   h2[trigger_nodes].
// ---------------------------------------------------------------------------

__global__ __launch_bounds__(256) void deg_kernel(
    const int* __restrict__ src, const int* __restrict__ dst,
    int* __restrict__ deg_out, int* __restrict__ deg_in, int E)
{
    int i = blockIdx.x * blockDim.x + threadIdx.x;
    if (i < E) {
        atomicAdd(&deg_out[src[i]], 1);
        atomicAdd(&deg_in[dst[i]], 1);
    }
}

__global__ __launch_bounds__(256) void norm_kernel(
    const int* __restrict__ deg_out, const int* __restrict__ deg_in,
    float* __restrict__ norm_out, float* __restrict__ norm_in, int N)
{
    int i = blockIdx.x * blockDim.x + threadIdx.x;
    if (i < N) {
        norm_out[i] = rsqrtf(fmaxf((float)deg_out[i], 1.0f));
        norm_in[i]  = rsqrtf(fmaxf((float)deg_in[i], 1.0f));
    }
}

// --- 3-kernel exclusive scan of deg_in into rowptr[1..N] (rowptr[0]=0) ---
__global__ __launch_bounds__(256) void scan1_kernel(
    const int* __restrict__ deg, int* __restrict__ rowptr,
    int* __restrict__ bsum, int N)
{
    __shared__ int s[256];
    int t = threadIdx.x;
    int i = blockIdx.x * 256 + t;
    s[t] = (i < N) ? deg[i] : 0;
    __syncthreads();
    #pragma unroll
    for (int off = 1; off < 256; off <<= 1) {
        int v = (t >= off) ? s[t - off] : 0;
        __syncthreads();
        s[t] += v;
        __syncthreads();
    }
    if (i < N) rowptr[i + 1] = s[t];
    if (t == 255) bsum[blockIdx.x] = s[255];
}

__global__ __launch_bounds__(256) void scan2_kernel(int* __restrict__ bsum, int nb)
{
    __shared__ int s[256];
    int t = threadIdx.x;
    s[t] = (t < nb) ? bsum[t] : 0;
    __syncthreads();
    #pragma unroll
    for (int off = 1; off < 256; off <<= 1) {
        int v = (t >= off) ? s[t - off] : 0;
        __syncthreads();
        s[t] += v;
        __syncthreads();
    }
    if (t < nb) bsum[t] = s[t];
}

__global__ __launch_bounds__(256) void scan3_kernel(
    int* __restrict__ rowptr, const int* __restrict__ bsum, int N)
{
    int b = blockIdx.x;
    int i = b * 256 + threadIdx.x;
    if (i < N) {
        int add = (b > 0) ? bsum[b - 1] : 0;
        rowptr[i + 1] += add;
    }
    if (i == 0) rowptr[0] = 0;
}

// ecol[rowptr[dst[e]] + slot] = src[e]
__global__ __launch_bounds__(256) void fill_kernel(
    const int* __restrict__ src, const int* __restrict__ dst,
    const int* __restrict__ rowptr, int* __restrict__ cursor,
    int* __restrict__ ecol, int E)
{
    int e = blockIdx.x * blockDim.x + threadIdx.x;
    if (e < E) {
        int r = dst[e];
        int slot = atomicAdd(&cursor[r], 1);
        ecol[rowptr[r] + slot] = src[e];
    }
}

// xs = x * norm_out[row]  (rowwise, float4)
__global__ __launch_bounds__(256) void prescale_kernel(
    const float* __restrict__ x, const float* __restrict__ s,
    float* __restrict__ out, long nvec /* = N*D/4 */, int dq /* = D/4 */)
{
    long i = (long)blockIdx.x * blockDim.x + threadIdx.x;
    long stride = (long)gridDim.x * blockDim.x;
    for (; i < nvec; i += stride) {
        long row = i / dq;
        float4 v = reinterpret_cast<const float4*>(x)[i];
        float ns = s[row];
        v.x *= ns; v.y *= ns; v.z *= ns; v.w *= ns;
        reinterpret_cast<float4*>(out)[i] = v;
    }
}

// out[r, :] = sum over in-edges of x[src, :]  (x pre-scaled by norm_out)
template<int D>
__global__ __launch_bounds__(D) void gather_kernel(
    const float* __restrict__ x, const int* __restrict__ rowptr,
    const int* __restrict__ ecol, float* __restrict__ out, int N)
{
    __shared__ int sE[D];
    const int r = blockIdx.x;
    if (r >= N) return;
    const int beg = rowptr[r], end = rowptr[r + 1];
    const int c = threadIdx.x;
    float acc = 0.0f;
    for (int base = beg; base < end; base += D) {
        const int cnt = min(D, end - base);
        __syncthreads();
        if (c < cnt) sE[c] = ecol[base + c];
        __syncthreads();
        for (int k = 0; k < cnt; ++k) {
            const int s = sE[k];
            acc += x[(long)s * D + c];
        }
    }
    out[(long)r * D + c] = acc;
}

// C[r, c] = act( sum_k rowscale[r'] * A[r', k] * B[k, c] + bias[c] ) * outscale[r]
// r' = gidx ? gidx[r] : r.  64x64 tile, 256 threads, 4x4 microtile.
template<bool RELU, bool GATHER>
__global__ __launch_bounds__(256) void gemm_kernel(
    const float* __restrict__ A, const float* __restrict__ B,
    const float* __restrict__ bias, const float* __restrict__ rowscale,
    const float* __restrict__ outscale, const int* __restrict__ gidx,
    float* __restrict__ C, int M, int N, int K)
{
    constexpr int TS = 64, KT = 16;
    __shared__ float As[KT][TS + 1];
    __shared__ float Bs[KT][TS + 1];

    const int tid = threadIdx.x;
    const int tx = tid & 15, ty = tid >> 4;
    const int row0 = blockIdx.y * TS;
    const int col0 = blockIdx.x * TS;

    const int am = tid >> 2, aq = tid & 3;
    const int arow = row0 + am;
    const bool avalid = (arow < M);
    long asrc = arow;
    float ascale = 1.0f;
    if (avalid) {
        if (GATHER) asrc = gidx[arow];
        if (rowscale) ascale = rowscale[asrc];
    }
    const int bk = tid >> 4, bq = tid & 15;

    float acc[4][4] = {};

    for (int kb = 0; kb < K; kb += KT) {
        float4 av = make_float4(0.f, 0.f, 0.f, 0.f);
        if (avalid)
            av = *reinterpret_cast<const float4*>(&A[asrc * K + kb + aq * 4]);
        const float4 bv =
            *reinterpret_cast<const float4*>(&B[(long)(kb + bk) * N + col0 + bq * 4]);

        As[aq * 4 + 0][am] = av.x * ascale;
        As[aq * 4 + 1][am] = av.y * ascale;
        As[aq * 4 + 2][am] = av.z * ascale;
        As[aq * 4 + 3][am] = av.w * ascale;
        Bs[bk][bq * 4 + 0] = bv.x;
        Bs[bk][bq * 4 + 1] = bv.y;
        Bs[bk][bq * 4 + 2] = bv.z;
        Bs[bk][bq * 4 + 3] = bv.w;
        __syncthreads();

        #pragma unroll
        for (int kk = 0; kk < KT; ++kk) {
            float a[4], b[4];
            #pragma unroll
            for (int i = 0; i < 4; ++i) a[i] = As[kk][ty * 4 + i];
            #pragma unroll
            for (int j = 0; j < 4; ++j) b[j] = Bs[kk][tx * 4 + j];
            #pragma unroll
            for (int i = 0; i < 4; ++i)
                #pragma unroll
                for (int j = 0; j < 4; ++j)
                    acc[i][j] = fmaf(a[i], b[j], acc[i][j]);
        }
        __syncthreads();
    }

    #pragma unroll
    for (int i = 0; i < 4; ++i) {
        const int r = row0 + ty * 4 + i;
        if (r >= M) continue;
        float osc = outscale ? outscale[r] : 1.0f;
        #pragma unroll
        for (int j = 0; j < 4; ++j) {
            const int c = col0 + tx * 4 + j;
            float v = acc[i][j] + bias[c];
            if (RELU) v = fmaxf(v, 0.0f);
            C[(long)r * N + c] = v * osc;
        }
    }
}

static inline long align4(long x) { return (x + 3) & ~3L; }

extern "C" void kernel_launch(void* const* d_in, const int* in_sizes, int n_in,
                              void* d_out, int out_size, void* d_ws, size_t ws_size,
                              hipStream_t stream)
{
    const float* features = (const float*)d_in[0];
    const int*   src      = (const int*)d_in[1];
    const int*   dst      = (const int*)d_in[2];
    const int*   trig     = (const int*)d_in[3];
    const float* W1  = (const float*)d_in[4];
    const float* b1  = (const float*)d_in[5];
    const float* W2  = (const float*)d_in[6];
    const float* b2  = (const float*)d_in[7];
    const float* Wf  = (const float*)d_in[8];
    const float* bf  = (const float*)d_in[9];
    const float* Wf1 = (const float*)d_in[10];
    const float* bf1 = (const float*)d_in[11];
    const float* We  = (const float*)d_in[12];
    const float* be  = (const float*)d_in[13];
    const float* We1 = (const float*)d_in[14];
    const float* be1 = (const float*)d_in[15];

    const int  d   = 128, h2d = 256, od = 64;
    const int  N   = in_sizes[0] / d;      // 50000
    const int  E   = in_sizes[1];          // 800000
    const int  T   = in_sizes[3];          // 4096
    const int  NB  = (N + 255) / 256;      // scan blocks (196 <= 256)

    // ---- workspace layout (4-byte elems, each region 16B-aligned) ----
    char* wsb = (char*)d_ws;
    long off = 0;
    auto takeF = [&](long n) { float* p = (float*)(wsb + off * 4); off += align4(n); return p; };
    auto takeI = [&](long n) { int*   p = (int*)  (wsb + off * 4); off += align4(n); return p; };

    float* norm_out = takeF(N);
    float* norm_in  = takeF(N);
    int*   rowptr   = takeI(N + 1);
    int*   degout   = takeI(N);        // deg_out counts
    int*   degin    = takeI(N);        // deg_in counts
    int*   cursor   = takeI(N);        // fill cursors
    int*   bsum     = takeI(256);
    int*   ecol     = takeI(E);
    float* bufA     = takeF((long)N * d);    // xs           | agg2 (lo half)
    float* bufB     = takeF((long)N * d);    // agg1         | agg2 (hi half)
    float* bufC     = takeF((long)N * h2d);  // h1s          | h2 (front N*d)

    float* xs   = bufA;
    float* agg1 = bufB;
    float* h1s  = bufC;
    float* agg2 = bufA;                // spans bufA+bufB = N*256
    float* h2   = bufC;                // reuse after agg2 gather
    float* tmpf = bufA;                // T*128, reuse after gemm2
    float* tmpe = bufA + (long)T * d;  // T*64

    float* out_feat = (float*)d_out;              // [T,128]
    float* out_edge = out_feat + (long)T * d;     // [T,64]

    // ---- CSR build + norms ----
    hipMemsetAsync(degout, 0, (size_t)N * sizeof(int), stream);
    hipMemsetAsync(degin,  0, (size_t)N * sizeof(int), stream);
    hipMemsetAsync(cursor, 0, (size_t)N * sizeof(int), stream);

    deg_kernel<<<dim3((E + 255) / 256), dim3(256), 0, stream>>>(
        src, dst, degout, degin, E);
    norm_kernel<<<dim3((N + 255) / 256), dim3(256), 0, stream>>>(
        degout, degin, norm_out, norm_in, N);
    scan1_kernel<<<dim3(NB), dim3(256), 0, stream>>>(degin, rowptr, bsum, N);
    scan2_kernel<<<dim3(1), dim3(256), 0, stream>>>(bsum, NB);
    scan3_kernel<<<dim3(NB), dim3(256), 0, stream>>>(rowptr, bsum, N);
    fill_kernel<<<dim3((E + 255) / 256), dim3(256), 0, stream>>>(
        src, dst, rowptr, cursor, ecol, E);

    // ---- layer 1 ----
    prescale_kernel<<<dim3(2048), dim3(256), 0, stream>>>(
        features, norm_out, xs, (long)N * (d / 4), d / 4);
    gather_kernel<128><<<dim3(N), dim3(128), 0, stream>>>(
        xs, rowptr, ecol, agg1, N);
    gemm_kernel<true, false><<<dim3(h2d / 64, (N + 63) / 64), dim3(256), 0, stream>>>(
        agg1, W1, b1, norm_in, norm_out, nullptr, h1s, N, h2d, d);

    // ---- layer 2 ----
    gather_kernel<256><<<dim3(N), dim3(256), 0, stream>>>(
        h1s, rowptr, ecol, agg2, N);
    gemm_kernel<true, false><<<dim3(d / 64, (N + 63) / 64), dim3(256), 0, stream>>>(
        agg2, W2, b2, norm_in, nullptr, nullptr, h2, N, d, h2d);

    // ---- feat head ----
    gemm_kernel<true, true><<<dim3(d / 64, T / 64), dim3(256), 0, stream>>>(
        h2, Wf, bf, nullptr, nullptr, trig, tmpf, T, d, d);
    gemm_kernel<false, false><<<dim3(d / 64, T / 64), dim3(256), 0, stream>>>(
        tmpf, Wf1, bf1, nullptr, nullptr, nullptr, out_feat, T, d, d);

    // ---- edge head ----
    gemm_kernel<true, true><<<dim3(od / 64, T / 64), dim3(256), 0, stream>>>(
        h2, We, be, nullptr, nullptr, trig, tmpe, T, od, d);
    gemm_kernel<false, false><<<dim3(od / 64, T / 64), dim3(256), 0, stream>>>(
        tmpe, We1, be1, nullptr, nullptr, nullptr, out_edge, T, od, od);
}

// Round 3
// 394.228 us; speedup vs baseline: 10.9217x; 1.3192x over previous
//
#include <hip/hip_runtime.h>
#include <hip/hip_bf16.h>

// ---------------------------------------------------------------------------
// Trojan_GCN round 3:
//  - CSR gather aggregation (no float atomics)
//  - layer-2 GEMM commuted before aggregation (aggregate at d=128, not 256)
//  - layer-2 aggregation restricted to trigger rows only (T=4096 of N=50000)
//  - 128x128-tile / 8x8-micro f32 GEMM with b128 LDS reads
//  - norm_out prescale fused into layer-1 gather
// ---------------------------------------------------------------------------

__global__ __launch_bounds__(256) void deg_kernel(
    const int* __restrict__ src, const int* __restrict__ dst,
    int* __restrict__ deg_out, int* __restrict__ deg_in, int E)
{
    int i = blockIdx.x * blockDim.x + threadIdx.x;
    if (i < E) {
        atomicAdd(&deg_out[src[i]], 1);
        atomicAdd(&deg_in[dst[i]], 1);
    }
}

__global__ __launch_bounds__(256) void norm_kernel(
    const int* __restrict__ deg_out, const int* __restrict__ deg_in,
    float* __restrict__ norm_out, float* __restrict__ norm_in, int N)
{
    int i = blockIdx.x * blockDim.x + threadIdx.x;
    if (i < N) {
        norm_out[i] = rsqrtf(fmaxf((float)deg_out[i], 1.0f));
        norm_in[i]  = rsqrtf(fmaxf((float)deg_in[i], 1.0f));
    }
}

// --- 3-kernel exclusive scan of deg_in into rowptr[1..N] (rowptr[0]=0) ---
__global__ __launch_bounds__(256) void scan1_kernel(
    const int* __restrict__ deg, int* __restrict__ rowptr,
    int* __restrict__ bsum, int N)
{
    __shared__ int s[256];
    int t = threadIdx.x;
    int i = blockIdx.x * 256 + t;
    s[t] = (i < N) ? deg[i] : 0;
    __syncthreads();
    #pragma unroll
    for (int off = 1; off < 256; off <<= 1) {
        int v = (t >= off) ? s[t - off] : 0;
        __syncthreads();
        s[t] += v;
        __syncthreads();
    }
    if (i < N) rowptr[i + 1] = s[t];
    if (t == 255) bsum[blockIdx.x] = s[255];
}

__global__ __launch_bounds__(256) void scan2_kernel(int* __restrict__ bsum, int nb)
{
    __shared__ int s[256];
    int t = threadIdx.x;
    s[t] = (t < nb) ? bsum[t] : 0;
    __syncthreads();
    #pragma unroll
    for (int off = 1; off < 256; off <<= 1) {
        int v = (t >= off) ? s[t - off] : 0;
        __syncthreads();
        s[t] += v;
        __syncthreads();
    }
    if (t < nb) bsum[t] = s[t];
}

__global__ __launch_bounds__(256) void scan3_kernel(
    int* __restrict__ rowptr, const int* __restrict__ bsum, int N)
{
    int b = blockIdx.x;
    int i = b * 256 + threadIdx.x;
    if (i < N) {
        int add = (b > 0) ? bsum[b - 1] : 0;
        rowptr[i + 1] += add;
    }
    if (i == 0) rowptr[0] = 0;
}

// ecol[rowptr[dst[e]] + slot] = src[e]
__global__ __launch_bounds__(256) void fill_kernel(
    const int* __restrict__ src, const int* __restrict__ dst,
    const int* __restrict__ rowptr, int* __restrict__ cursor,
    int* __restrict__ ecol, int E)
{
    int e = blockIdx.x * blockDim.x + threadIdx.x;
    if (e < E) {
        int r = dst[e];
        int slot = atomicAdd(&cursor[r], 1);
        ecol[rowptr[r] + slot] = src[e];
    }
}

// out[r, c] = sum_{e in-edges of r} x[src_e, c] * nsrc[src_e]     (D = 128)
__global__ __launch_bounds__(128) void gather_scale_kernel(
    const float* __restrict__ x, const float* __restrict__ nsrc,
    const int* __restrict__ rowptr, const int* __restrict__ ecol,
    float* __restrict__ out, int N)
{
    constexpr int D = 128;
    __shared__ int   sE[D];
    __shared__ float sS[D];
    const int r = blockIdx.x;
    if (r >= N) return;
    const int beg = rowptr[r], end = rowptr[r + 1];
    const int c = threadIdx.x;
    float acc = 0.0f;
    for (int base = beg; base < end; base += D) {
        const int cnt = min(D, end - base);
        __syncthreads();
        if (c < cnt) {
            int s = ecol[base + c];
            sE[c] = s;
            sS[c] = nsrc[s];
        }
        __syncthreads();
        for (int k = 0; k < cnt; ++k)
            acc = fmaf(x[(long)sE[k] * D + c], sS[k], acc);
    }
    out[(long)r * D + c] = acc;
}

// h2t[b, c] = relu( norm_in[r] * sum_{e in-edges of r} z[src_e, c] + b2[c] ),
// r = trig[b]   (D = 128)
__global__ __launch_bounds__(128) void gather_trig_kernel(
    const float* __restrict__ z, const int* __restrict__ trig,
    const float* __restrict__ norm_in, const float* __restrict__ b2,
    const int* __restrict__ rowptr, const int* __restrict__ ecol,
    float* __restrict__ h2t, int T)
{
    constexpr int D = 128;
    __shared__ int sE[D];
    const int b = blockIdx.x;
    if (b >= T) return;
    const int r = trig[b];
    const int beg = rowptr[r], end = rowptr[r + 1];
    const int c = threadIdx.x;
    float acc = 0.0f;
    for (int base = beg; base < end; base += D) {
        const int cnt = min(D, end - base);
        __syncthreads();
        if (c < cnt) sE[c] = ecol[base + c];
        __syncthreads();
        for (int k = 0; k < cnt; ++k)
            acc += z[(long)sE[k] * D + c];
    }
    h2t[(long)b * D + c] = fmaxf(fmaf(norm_in[r], acc, b2[c]), 0.0f);
}

// C[r, c] = act( rowscale[r] * sum_k A[r, k] * B[k, c] + bias[c] ) * outscale[r]
// TM x TN tile, 256 threads (16x16), MR x NR micro. Requires N % TN == 0,
// K % 16 == 0; M may be ragged.
template<int TM, int TN, int MR, int NR, bool RELU>
__global__ __launch_bounds__(256) void gemm_kernel(
    const float* __restrict__ A, const float* __restrict__ B,
    const float* __restrict__ bias, const float* __restrict__ rowscale,
    const float* __restrict__ outscale,
    float* __restrict__ C, int M, int N, int K)
{
    constexpr int KT = 16;
    static_assert(TM / 16 == MR && TN / 16 == NR, "layout");
    constexpr int ALOADS = TM * KT / 4 / 256;
    constexpr int BLOADS = KT * TN / 4 / 256;

    __shared__ float As[KT][TM];
    __shared__ float Bs[KT][TN];

    const int tid = threadIdx.x;
    const int tx = tid & 15, ty = tid >> 4;
    const int row0 = blockIdx.y * TM;
    const int col0 = blockIdx.x * TN;

    // hoisted A-load roles
    int   am_[ALOADS], aq_[ALOADS];
    long  abase_[ALOADS];
    float asc_[ALOADS];
    bool  aval_[ALOADS];
    #pragma unroll
    for (int l = 0; l < ALOADS; ++l) {
        int idx = tid + l * 256;
        am_[l] = idx >> 2;
        aq_[l] = idx & 3;
        int ar = row0 + am_[l];
        aval_[l] = (ar < M);
        abase_[l] = (long)(aval_[l] ? ar : 0) * K;
        asc_[l] = 1.0f;
        if (aval_[l] && rowscale) asc_[l] = rowscale[ar];
    }

    float acc[MR][NR] = {};

    for (int kb = 0; kb < K; kb += KT) {
        #pragma unroll
        for (int l = 0; l < ALOADS; ++l) {
            float4 av = make_float4(0.f, 0.f, 0.f, 0.f);
            if (aval_[l])
                av = *reinterpret_cast<const float4*>(&A[abase_[l] + kb + aq_[l] * 4]);
            const float sc = asc_[l];
            As[aq_[l] * 4 + 0][am_[l]] = av.x * sc;
            As[aq_[l] * 4 + 1][am_[l]] = av.y * sc;
            As[aq_[l] * 4 + 2][am_[l]] = av.z * sc;
            As[aq_[l] * 4 + 3][am_[l]] = av.w * sc;
        }
        #pragma unroll
        for (int l = 0; l < BLOADS; ++l) {
            int idx = tid + l * 256;
            int bk = idx / (TN / 4), bq = idx % (TN / 4);
            const float4 bv =
                *reinterpret_cast<const float4*>(&B[(long)(kb + bk) * N + col0 + bq * 4]);
            *reinterpret_cast<float4*>(&Bs[bk][bq * 4]) = bv;
        }
        __syncthreads();

        #pragma unroll
        for (int kk = 0; kk < KT; ++kk) {
            float a[MR], b[NR];
            #pragma unroll
            for (int i = 0; i < MR / 4; ++i)
                *reinterpret_cast<float4*>(&a[i * 4]) =
                    *reinterpret_cast<const float4*>(&As[kk][ty * MR + i * 4]);
            #pragma unroll
            for (int j = 0; j < NR / 4; ++j)
                *reinterpret_cast<float4*>(&b[j * 4]) =
                    *reinterpret_cast<const float4*>(&Bs[kk][tx * NR + j * 4]);
            #pragma unroll
            for (int i = 0; i < MR; ++i)
                #pragma unroll
                for (int j = 0; j < NR; ++j)
                    acc[i][j] = fmaf(a[i], b[j], acc[i][j]);
        }
        __syncthreads();
    }

    #pragma unroll
    for (int i = 0; i < MR; ++i) {
        const int r = row0 + ty * MR + i;
        if (r >= M) continue;
        const float osc = outscale ? outscale[r] : 1.0f;
        #pragma unroll
        for (int j = 0; j < NR; ++j) {
            const int c = col0 + tx * NR + j;
            float v = acc[i][j] + (bias ? bias[c] : 0.0f);
            if (RELU) v = fmaxf(v, 0.0f);
            C[(long)r * N + c] = v * osc;
        }
    }
}

static inline long align4(long x) { return (x + 3) & ~3L; }

extern "C" void kernel_launch(void* const* d_in, const int* in_sizes, int n_in,
                              void* d_out, int out_size, void* d_ws, size_t ws_size,
                              hipStream_t stream)
{
    const float* features = (const float*)d_in[0];
    const int*   src      = (const int*)d_in[1];
    const int*   dst      = (const int*)d_in[2];
    const int*   trig     = (const int*)d_in[3];
    const float* W1  = (const float*)d_in[4];
    const float* b1  = (const float*)d_in[5];
    const float* W2  = (const float*)d_in[6];
    const float* b2  = (const float*)d_in[7];
    const float* Wf  = (const float*)d_in[8];
    const float* bf  = (const float*)d_in[9];
    const float* Wf1 = (const float*)d_in[10];
    const float* bf1 = (const float*)d_in[11];
    const float* We  = (const float*)d_in[12];
    const float* be  = (const float*)d_in[13];
    const float* We1 = (const float*)d_in[14];
    const float* be1 = (const float*)d_in[15];

    const int  d   = 128, h2d = 256, od = 64;
    const int  N   = in_sizes[0] / d;      // 50000
    const int  E   = in_sizes[1];          // 800000
    const int  T   = in_sizes[3];          // 4096
    const int  NB  = (N + 255) / 256;      // 196 <= 256

    // ---- workspace layout ----
    char* wsb = (char*)d_ws;
    long off = 0;
    auto takeF = [&](long n) { float* p = (float*)(wsb + off * 4); off += align4(n); return p; };
    auto takeI = [&](long n) { int*   p = (int*)  (wsb + off * 4); off += align4(n); return p; };

    float* norm_out = takeF(N);
    float* norm_in  = takeF(N);
    int*   rowptr   = takeI(N + 1);
    int*   degout   = takeI(N);
    int*   degin    = takeI(N);
    int*   cursor   = takeI(N);
    int*   bsum     = takeI(256);
    int*   ecol     = takeI(E);
    float* agg1     = takeF((long)N * d);    // [N,128]
    float* z        = takeF((long)N * d);    // [N,128]
    float* h1s      = takeF((long)N * h2d);  // [N,256]
    float* h2t      = takeF((long)T * d);    // [T,128]
    float* tmpf     = takeF((long)T * d);    // [T,128]
    float* tmpe     = takeF((long)T * od);   // [T,64]

    float* out_feat = (float*)d_out;              // [T,128]
    float* out_edge = out_feat + (long)T * d;     // [T,64]

    // ---- CSR build + norms ----
    hipMemsetAsync(degout, 0, (size_t)N * sizeof(int), stream);
    hipMemsetAsync(degin,  0, (size_t)N * sizeof(int), stream);
    hipMemsetAsync(cursor, 0, (size_t)N * sizeof(int), stream);

    deg_kernel<<<dim3((E + 255) / 256), dim3(256), 0, stream>>>(
        src, dst, degout, degin, E);
    norm_kernel<<<dim3((N + 255) / 256), dim3(256), 0, stream>>>(
        degout, degin, norm_out, norm_in, N);
    scan1_kernel<<<dim3(NB), dim3(256), 0, stream>>>(degin, rowptr, bsum, N);
    scan2_kernel<<<dim3(1), dim3(256), 0, stream>>>(bsum, NB);
    scan3_kernel<<<dim3(NB), dim3(256), 0, stream>>>(rowptr, bsum, N);
    fill_kernel<<<dim3((E + 255) / 256), dim3(256), 0, stream>>>(
        src, dst, rowptr, cursor, ecol, E);

    // ---- layer 1: agg1 = A @ (features * norm_out); h1s = relu(ni*agg1@W1+b1)*no
    gather_scale_kernel<<<dim3(N), dim3(128), 0, stream>>>(
        features, norm_out, rowptr, ecol, agg1, N);
    gemm_kernel<128, 128, 8, 8, true>
        <<<dim3(h2d / 128, (N + 127) / 128), dim3(256), 0, stream>>>(
        agg1, W1, b1, norm_in, norm_out, h1s, N, h2d, d);

    // ---- layer 2 (commuted): z = h1s @ W2; h2t = relu(ni*(A@z)[trig] + b2)
    gemm_kernel<128, 64, 8, 4, false>
        <<<dim3(d / 64, (N + 127) / 128), dim3(256), 0, stream>>>(
        h1s, W2, nullptr, nullptr, nullptr, z, N, d, h2d);
    gather_trig_kernel<<<dim3(T), dim3(128), 0, stream>>>(
        z, trig, norm_in, b2, rowptr, ecol, h2t, T);

    // ---- feat head: out_feat = (relu(h2t @ Wf + bf)) @ Wf1 + bf1
    gemm_kernel<64, 64, 4, 4, true>
        <<<dim3(d / 64, (T + 63) / 64), dim3(256), 0, stream>>>(
        h2t, Wf, bf, nullptr, nullptr, tmpf, T, d, d);
    gemm_kernel<64, 64, 4, 4, false>
        <<<dim3(d / 64, (T + 63) / 64), dim3(256), 0, stream>>>(
        tmpf, Wf1, bf1, nullptr, nullptr, out_feat, T, d, d);

    // ---- edge head: out_edge = (relu(h2t @ We + be)) @ We1 + be1
    gemm_kernel<64, 64, 4, 4, true>
        <<<dim3(od / 64, (T + 63) / 64), dim3(256), 0, stream>>>(
        h2t, We, be, nullptr, nullptr, tmpe, T, od, d);
    gemm_kernel<64, 64, 4, 4, false>
        <<<dim3(od / 64, (T + 63) / 64), dim3(256), 0, stream>>>(
        tmpe, We1, be1, nullptr, nullptr, out_edge, T, od, od);
}